// Round 2
// baseline (31940.808 us; speedup 1.0000x reference)
//
#include <hip/hip_runtime.h>
#include <hip/hip_fp16.h>

// Problem dims (fixed by the reference)
#define T_DIM 4096
#define I_DIM 512
#define H_DIM 1024
#define O_DIM 256

// Recurrence kernel geometry
#define NWG 64        // persistent workgroups (<= 256 CUs -> all co-resident)
#define RTHREADS 256  // 4 waves; 64 rows/WG x 4 k-lanes/row

typedef _Float16 half2v __attribute__((ext_vector_type(2)));

__device__ __forceinline__ float sigmoid_fast(float x) {
    return 1.f / (1.f + __expf(-x));
}
__device__ __forceinline__ float tanh_fast(float x) {
    float ax = fabsf(x);
    float e  = __expf(-2.f * ax);
    float t  = (1.f - e) / (1.f + e);
    return copysignf(t, x);
}

// fp16 dot2 with fp32 accumulate; uses v_dot2_f32_f16 when available.
__device__ __forceinline__ float dot2u(unsigned int a, unsigned int b, float c) {
#if __has_builtin(__builtin_amdgcn_fdot2)
    return __builtin_amdgcn_fdot2(__builtin_bit_cast(half2v, a),
                                  __builtin_bit_cast(half2v, b), c, false);
#else
    half2v ha = __builtin_bit_cast(half2v, a);
    half2v hb = __builtin_bit_cast(half2v, b);
    return c + (float)ha.x * (float)hb.x + (float)ha.y * (float)hb.y;
#endif
}

// ---------------------------------------------------------------------------
// Kernel A1: pack the 4 Wx matrices into one [4096][512] row-major buffer and
// the 4 biases into bpack[4096]. Row R = g*1024 + h, gate order f,i,c,o.
// ---------------------------------------------------------------------------
__global__ void pack_wx_bias(const float* __restrict__ wxf, const float* __restrict__ wxi,
                             const float* __restrict__ wxc, const float* __restrict__ wxo,
                             const float* __restrict__ bf,  const float* __restrict__ bi,
                             const float* __restrict__ bc,  const float* __restrict__ bo,
                             float* __restrict__ wxp, float* __restrict__ bpack) {
    int idx = blockIdx.x * 256 + threadIdx.x;
    const int total = 4 * H_DIM * I_DIM;
    if (idx < total) {
        int R = idx >> 9;          // / I_DIM
        int k = idx & (I_DIM - 1);
        int g = R >> 10;
        int h = R & (H_DIM - 1);
        const float* w = (g == 0) ? wxf : (g == 1) ? wxi : (g == 2) ? wxc : wxo;
        wxp[idx] = w[h * I_DIM + k];
    }
    if (idx < 4 * H_DIM) {
        int g = idx >> 10, h = idx & (H_DIM - 1);
        const float* b = (g == 0) ? bf : (g == 1) ? bi : (g == 2) ? bc : bo;
        bpack[idx] = b[h];
    }
}

// ---------------------------------------------------------------------------
// Kernel A2: convert Wh_* to fp16 in the exact per-thread layout the
// recurrence kernel loads: wh16[((wg*256+tid)*256)+e], where thread (wg,tid)
// owns gate g=(tid>>6), jj=(tid>>2)&15 (j = wg*16+jj), k-slice q=tid&3,
// element k = q*256+e.
// ---------------------------------------------------------------------------
__global__ void pack_wh_f16(const float* __restrict__ whf, const float* __restrict__ whi,
                            const float* __restrict__ whc, const float* __restrict__ who,
                            __half* __restrict__ wh16) {
    int d = blockIdx.x * 256 + threadIdx.x;
    if (d >= 4 * H_DIM * H_DIM) return;
    int wg  = d >> 16;
    int tid = (d >> 8) & 255;
    int e   = d & 255;
    int g = (tid >> 6) & 3;
    int jj = (tid >> 2) & 15;
    int q = tid & 3;
    int j = wg * 16 + jj;
    int k = q * 256 + e;
    const float* w = (g == 0) ? whf : (g == 1) ? whi : (g == 2) ? whc : who;
    wh16[d] = __float2half(w[j * H_DIM + k]);
}

// ---------------------------------------------------------------------------
// Shared fp32 GEMM: C[M][N] = A[M][K] * B[N][K]^T + bias[N]
// Tiles 64x64, BK=16, 256 threads, 4x4 accum per thread. All dims divide.
// ---------------------------------------------------------------------------
#define BM 64
#define BN 64
#define BK 16
__global__ __launch_bounds__(256) void gemm_bt(const float* __restrict__ A,
                                               const float* __restrict__ B,
                                               const float* __restrict__ bias,
                                               float* __restrict__ C,
                                               int M, int N, int K) {
    __shared__ float As[BK][BM + 4];
    __shared__ float Bs[BK][BN + 4];
    int tid = threadIdx.x;
    int m0 = blockIdx.y * BM, n0 = blockIdx.x * BN;
    int tx = tid & 15, ty = tid >> 4;
    float acc[4][4] = {};
    for (int k0 = 0; k0 < K; k0 += BK) {
#pragma unroll
        for (int l = 0; l < 4; ++l) {
            int idx = tid + l * 256;     // 0..1023
            int m = idx >> 4, k = idx & 15;
            As[k][m] = A[(long)(m0 + m) * K + k0 + k];
            Bs[k][m] = B[(long)(n0 + m) * K + k0 + k];
        }
        __syncthreads();
#pragma unroll
        for (int kk = 0; kk < BK; ++kk) {
            float ra[4], rb[4];
#pragma unroll
            for (int i = 0; i < 4; ++i) ra[i] = As[kk][ty * 4 + i];
#pragma unroll
            for (int j = 0; j < 4; ++j) rb[j] = Bs[kk][tx * 4 + j];
#pragma unroll
            for (int i = 0; i < 4; ++i)
#pragma unroll
                for (int j = 0; j < 4; ++j) acc[i][j] += ra[i] * rb[j];
        }
        __syncthreads();
    }
#pragma unroll
    for (int i = 0; i < 4; ++i) {
        int m = m0 + ty * 4 + i;
#pragma unroll
        for (int j = 0; j < 4; ++j) {
            int n = n0 + tx * 4 + j;
            C[(long)m * N + n] = acc[i][j] + bias[n];
        }
    }
}

// ---------------------------------------------------------------------------
// Kernel C: persistent recurrence. 64 WGs x 256 threads; weights in VGPRs
// (fp16, 128 half2/thread). Per step: 4 matvec rows per WG-row-group via
// v_dot2, shfl reduce over 4 k-lanes, gates+state update by 16 threads,
// h broadcast through double-buffered global fp16 buffer, device-scope
// counting barrier.
// ---------------------------------------------------------------------------
__global__ __launch_bounds__(RTHREADS, 1) void lstm_recurrence(
    const float* __restrict__ gx,          // [T][4*H]
    const unsigned int* __restrict__ wh16, // packed half2
    __half* __restrict__ hbuf,             // [2][H]
    float* __restrict__ hs,                // [T][H]
    unsigned int* __restrict__ ctr) {
    const int wg = blockIdx.x, tid = threadIdx.x;
    const int g = (tid >> 6) & 3;
    const int jj = (tid >> 2) & 15;
    const int q = tid & 3;
    const int j = wg * 16 + jj;
    const int R = g * H_DIM + j;

    __shared__ float lds_gate[4][16];
    __shared__ float lds_c[16];
    if (tid < 16) lds_c[tid] = 0.f;

    // Load this thread's 256 fp16 weights (32 x uint4 = 128 half2) into regs.
    uint4 w[32];
    const uint4* wp = (const uint4*)wh16 + ((long)(wg * RTHREADS + tid)) * 32;
#pragma unroll
    for (int i = 0; i < 32; ++i) w[i] = wp[i];

    float gx_next = gx[R];  // t = 0 pre-activation for this row
    __syncthreads();

    for (int t = 0; t < T_DIM; ++t) {
        float gxv = gx_next;
        if (t + 1 < T_DIM) gx_next = gx[(long)(t + 1) * (4 * H_DIM) + R];  // prefetch

        // h chunk for this k-slice: halves [q*256, q*256+256) of hbuf[t&1]
        const uint4* hb = (const uint4*)(hbuf + (t & 1) * H_DIM) + q * 32;
        float a0 = 0.f, a1 = 0.f, a2 = 0.f, a3 = 0.f;
#pragma unroll
        for (int i = 0; i < 32; ++i) {
            uint4 hv = hb[i];
            uint4 wv = w[i];
            a0 = dot2u(hv.x, wv.x, a0);
            a1 = dot2u(hv.y, wv.y, a1);
            a2 = dot2u(hv.z, wv.z, a2);
            a3 = dot2u(hv.w, wv.w, a3);
        }
        float s = (a0 + a1) + (a2 + a3);
        s += __shfl_xor(s, 1);
        s += __shfl_xor(s, 2);
        if (q == 0) lds_gate[g][jj] = s + gxv;
        __syncthreads();

        if (tid < 16) {
            float gf = lds_gate[0][tid], gi = lds_gate[1][tid];
            float gc = lds_gate[2][tid], go = lds_gate[3][tid];
            float c  = lds_c[tid];
            float f  = sigmoid_fast(gf);
            float ii = sigmoid_fast(gi);
            float cd = tanh_fast(gc);
            float o  = sigmoid_fast(go);
            float cn = f * c + ii * cd;
            float hn = o * cn;  // reference omits tanh(c_t)
            lds_c[tid] = cn;
            int jg = wg * 16 + tid;
            hbuf[((t + 1) & 1) * H_DIM + jg] = __float2half(hn);
            hs[(long)t * H_DIM + jg] = hn;
        }
        __syncthreads();

        if (tid == 0) {
            __builtin_amdgcn_fence(__ATOMIC_RELEASE, "agent");
            __hip_atomic_fetch_add(ctr, 1u, __ATOMIC_RELAXED, __HIP_MEMORY_SCOPE_AGENT);
            const unsigned int target = (unsigned int)(NWG * (t + 1));
            while (__hip_atomic_load(ctr, __ATOMIC_RELAXED, __HIP_MEMORY_SCOPE_AGENT) < target)
                __builtin_amdgcn_s_sleep(2);
            __builtin_amdgcn_fence(__ATOMIC_ACQUIRE, "agent");
        }
        __syncthreads();
    }
}

// ---------------------------------------------------------------------------
extern "C" void kernel_launch(void* const* d_in, const int* in_sizes, int n_in,
                              void* d_out, int out_size, void* d_ws, size_t ws_size,
                              hipStream_t stream) {
    (void)in_sizes; (void)n_in; (void)out_size; (void)ws_size;
    const float* x    = (const float*)d_in[0];
    const float* wxf  = (const float*)d_in[1];
    const float* whf  = (const float*)d_in[2];
    const float* bf   = (const float*)d_in[3];
    const float* wxi  = (const float*)d_in[4];
    const float* whi  = (const float*)d_in[5];
    const float* bi   = (const float*)d_in[6];
    const float* wxc  = (const float*)d_in[7];
    const float* whc  = (const float*)d_in[8];
    const float* bc   = (const float*)d_in[9];
    const float* wxo  = (const float*)d_in[10];
    const float* who  = (const float*)d_in[11];
    const float* bo   = (const float*)d_in[12];
    const float* wy   = (const float*)d_in[13];
    const float* by   = (const float*)d_in[14];
    float* y_out = (float*)d_out;

    // Workspace layout (bytes)
    char* base = (char*)d_ws;
    float*  gx    = (float*)(base + 0);                       // 64 MB: [T][4H]
    float*  wxp   = (float*)(base + (size_t)64 * 1024 * 1024);// 8 MB
    float*  bpack = (float*)(base + (size_t)72 * 1024 * 1024);// 16 KB
    __half* wh16  = (__half*)(base + (size_t)72 * 1024 * 1024 + 16384); // 8 MB
    float*  hs    = (float*)(base + (size_t)80 * 1024 * 1024 + 16384);  // 16 MB
    __half* hbuf  = (__half*)(base + (size_t)96 * 1024 * 1024 + 16384); // 4 KB
    unsigned int* ctr = (unsigned int*)(base + (size_t)96 * 1024 * 1024 + 16384 + 4096);

    // Zero h0 double-buffer + barrier counter (ws is poisoned 0xAA each run).
    hipMemsetAsync(hbuf, 0, 4096 + 64, stream);

    pack_wx_bias<<<(4 * H_DIM * I_DIM + 255) / 256, 256, 0, stream>>>(
        wxf, wxi, wxc, wxo, bf, bi, bc, bo, wxp, bpack);
    pack_wh_f16<<<(4 * H_DIM * H_DIM + 255) / 256, 256, 0, stream>>>(
        whf, whi, whc, who, wh16);

    // gx = x @ WxPack^T + bPack : [4096, 4096]
    gemm_bt<<<dim3((4 * H_DIM) / BN, T_DIM / BM), 256, 0, stream>>>(
        x, wxp, bpack, gx, T_DIM, 4 * H_DIM, I_DIM);

    lstm_recurrence<<<NWG, RTHREADS, 0, stream>>>(
        gx, (const unsigned int*)wh16, hbuf, hs, ctr);

    // y = hs @ Wy^T + by : [4096, 256]
    gemm_bt<<<dim3(O_DIM / BN, T_DIM / BM), 256, 0, stream>>>(
        hs, wy, by, y_out, T_DIM, O_DIM, H_DIM);
}

// Round 3
// 31906.110 us; speedup vs baseline: 1.0011x; 1.0011x over previous
//
#include <hip/hip_runtime.h>
#include <hip/hip_fp16.h>

// Problem dims (fixed by the reference)
#define T_DIM 4096
#define I_DIM 512
#define H_DIM 1024
#define O_DIM 256

// Recurrence kernel geometry
#define NWG 64        // persistent workgroups (<= 256 CUs -> all co-resident)
#define RTHREADS 256  // 4 waves; 64 rows/WG x 4 k-lanes/row

typedef _Float16 half2v __attribute__((ext_vector_type(2)));

__device__ __forceinline__ float sigmoid_fast(float x) {
    return 1.f / (1.f + __expf(-x));
}
__device__ __forceinline__ float tanh_fast(float x) {
    float ax = fabsf(x);
    float e  = __expf(-2.f * ax);
    float t  = (1.f - e) / (1.f + e);
    return copysignf(t, x);
}

// fp16 dot2 with fp32 accumulate; uses v_dot2_f32_f16 when available.
__device__ __forceinline__ float dot2u(unsigned int a, unsigned int b, float c) {
#if __has_builtin(__builtin_amdgcn_fdot2)
    return __builtin_amdgcn_fdot2(__builtin_bit_cast(half2v, a),
                                  __builtin_bit_cast(half2v, b), c, false);
#else
    half2v ha = __builtin_bit_cast(half2v, a);
    half2v hb = __builtin_bit_cast(half2v, b);
    return c + (float)ha.x * (float)hb.x + (float)ha.y * (float)hb.y;
#endif
}

// ---------------------------------------------------------------------------
// Kernel A1: pack the 4 Wx matrices into one [4096][512] row-major buffer and
// the 4 biases into bpack[4096]. Row R = g*1024 + h, gate order f,i,c,o.
// ---------------------------------------------------------------------------
__global__ void pack_wx_bias(const float* __restrict__ wxf, const float* __restrict__ wxi,
                             const float* __restrict__ wxc, const float* __restrict__ wxo,
                             const float* __restrict__ bf,  const float* __restrict__ bi,
                             const float* __restrict__ bc,  const float* __restrict__ bo,
                             float* __restrict__ wxp, float* __restrict__ bpack) {
    int idx = blockIdx.x * 256 + threadIdx.x;
    const int total = 4 * H_DIM * I_DIM;
    if (idx < total) {
        int R = idx >> 9;          // / I_DIM
        int k = idx & (I_DIM - 1);
        int g = R >> 10;
        int h = R & (H_DIM - 1);
        const float* w = (g == 0) ? wxf : (g == 1) ? wxi : (g == 2) ? wxc : wxo;
        wxp[idx] = w[h * I_DIM + k];
    }
    if (idx < 4 * H_DIM) {
        int g = idx >> 10, h = idx & (H_DIM - 1);
        const float* b = (g == 0) ? bf : (g == 1) ? bi : (g == 2) ? bc : bo;
        bpack[idx] = b[h];
    }
}

// ---------------------------------------------------------------------------
// Kernel A2: convert Wh_* to fp16 in the exact per-thread layout the
// recurrence kernel loads: wh16[((wg*256+tid)*256)+e], where thread (wg,tid)
// owns gate g=(tid>>6), jj=(tid>>2)&15 (j = wg*16+jj), k-slice q=tid&3,
// element k = q*256+e.
// ---------------------------------------------------------------------------
__global__ void pack_wh_f16(const float* __restrict__ whf, const float* __restrict__ whi,
                            const float* __restrict__ whc, const float* __restrict__ who,
                            __half* __restrict__ wh16) {
    int d = blockIdx.x * 256 + threadIdx.x;
    if (d >= 4 * H_DIM * H_DIM) return;
    int wg  = d >> 16;
    int tid = (d >> 8) & 255;
    int e   = d & 255;
    int g = (tid >> 6) & 3;
    int jj = (tid >> 2) & 15;
    int q = tid & 3;
    int j = wg * 16 + jj;
    int k = q * 256 + e;
    const float* w = (g == 0) ? whf : (g == 1) ? whi : (g == 2) ? whc : who;
    wh16[d] = __float2half(w[j * H_DIM + k]);
}

// ---------------------------------------------------------------------------
// Shared fp32 GEMM: C[M][N] = A[M][K] * B[N][K]^T + bias[N]
// Tiles 64x64, BK=16, 256 threads, 4x4 accum per thread. All dims divide.
// ---------------------------------------------------------------------------
#define BM 64
#define BN 64
#define BK 16
__global__ __launch_bounds__(256) void gemm_bt(const float* __restrict__ A,
                                               const float* __restrict__ B,
                                               const float* __restrict__ bias,
                                               float* __restrict__ C,
                                               int M, int N, int K) {
    __shared__ float As[BK][BM + 4];
    __shared__ float Bs[BK][BN + 4];
    int tid = threadIdx.x;
    int m0 = blockIdx.y * BM, n0 = blockIdx.x * BN;
    int tx = tid & 15, ty = tid >> 4;
    float acc[4][4] = {};
    for (int k0 = 0; k0 < K; k0 += BK) {
#pragma unroll
        for (int l = 0; l < 4; ++l) {
            int idx = tid + l * 256;     // 0..1023
            int m = idx >> 4, k = idx & 15;
            As[k][m] = A[(long)(m0 + m) * K + k0 + k];
            Bs[k][m] = B[(long)(n0 + m) * K + k0 + k];
        }
        __syncthreads();
#pragma unroll
        for (int kk = 0; kk < BK; ++kk) {
            float ra[4], rb[4];
#pragma unroll
            for (int i = 0; i < 4; ++i) ra[i] = As[kk][ty * 4 + i];
#pragma unroll
            for (int j = 0; j < 4; ++j) rb[j] = Bs[kk][tx * 4 + j];
#pragma unroll
            for (int i = 0; i < 4; ++i)
#pragma unroll
                for (int j = 0; j < 4; ++j) acc[i][j] += ra[i] * rb[j];
        }
        __syncthreads();
    }
#pragma unroll
    for (int i = 0; i < 4; ++i) {
        int m = m0 + ty * 4 + i;
#pragma unroll
        for (int j = 0; j < 4; ++j) {
            int n = n0 + tx * 4 + j;
            C[(long)m * N + n] = acc[i][j] + bias[n];
        }
    }
}

// ---------------------------------------------------------------------------
// Kernel C: persistent recurrence. 64 WGs x 256 threads. Per step: 4 matvec
// rows per WG-row-group via v_dot2, shfl reduce over 4 k-lanes, gates+state
// update by 16 threads, h broadcast through double-buffered global fp16
// buffer. Synchronization: per-WG TIMESTAMP FLAGS (128B-padded, release
// stores, no RMW) polled in parallel by wave 0 (lane L watches flag L,
// ballot-combined) — avoids the serialized single-line atomic-add storm.
// ---------------------------------------------------------------------------
__global__ __launch_bounds__(RTHREADS, 1) void lstm_recurrence(
    const float* __restrict__ gx,          // [T][4*H]
    const unsigned int* __restrict__ wh16, // packed half2
    __half* __restrict__ hbuf,             // [2][H]
    float* __restrict__ hs,                // [T][H]
    unsigned int* __restrict__ flags) {    // [NWG][32] padded timestamps
    const int wg = blockIdx.x, tid = threadIdx.x;
    const int g = (tid >> 6) & 3;
    const int jj = (tid >> 2) & 15;
    const int q = tid & 3;
    const int j = wg * 16 + jj;
    const int R = g * H_DIM + j;

    __shared__ float lds_gate[4][16];
    __shared__ float lds_c[16];
    if (tid < 16) lds_c[tid] = 0.f;

    // This thread's 256 fp16 weights (32 x uint4 = 128 half2).
    uint4 w[32];
    const uint4* wp = (const uint4*)wh16 + ((long)(wg * RTHREADS + tid)) * 32;
#pragma unroll
    for (int i = 0; i < 32; ++i) w[i] = wp[i];

    float gx_next = gx[R];  // t = 0 pre-activation for this row
    __syncthreads();

    for (int t = 0; t < T_DIM; ++t) {
        float gxv = gx_next;
        if (t + 1 < T_DIM) gx_next = gx[(long)(t + 1) * (4 * H_DIM) + R];  // prefetch

        // h chunk for this k-slice: halves [q*256, q*256+256) of hbuf[t&1]
        const uint4* hb = (const uint4*)(hbuf + (t & 1) * H_DIM) + q * 32;
        float a0 = 0.f, a1 = 0.f, a2 = 0.f, a3 = 0.f;
#pragma unroll
        for (int i = 0; i < 32; ++i) {
            uint4 hv = hb[i];
            uint4 wv = w[i];
            a0 = dot2u(hv.x, wv.x, a0);
            a1 = dot2u(hv.y, wv.y, a1);
            a2 = dot2u(hv.z, wv.z, a2);
            a3 = dot2u(hv.w, wv.w, a3);
        }
        float s = (a0 + a1) + (a2 + a3);
        s += __shfl_xor(s, 1);
        s += __shfl_xor(s, 2);
        if (q == 0) lds_gate[g][jj] = s + gxv;
        __syncthreads();

        if (tid < 16) {
            float gf = lds_gate[0][tid], gi = lds_gate[1][tid];
            float gc = lds_gate[2][tid], go = lds_gate[3][tid];
            float c  = lds_c[tid];
            float f  = sigmoid_fast(gf);
            float ii = sigmoid_fast(gi);
            float cd = tanh_fast(gc);
            float o  = sigmoid_fast(go);
            float cn = f * c + ii * cd;
            float hn = o * cn;  // reference omits tanh(c_t)
            lds_c[tid] = cn;
            int jg = wg * 16 + tid;
            hbuf[((t + 1) & 1) * H_DIM + jg] = __float2half(hn);
            hs[(long)t * H_DIM + jg] = hn;
        }
        // Release-store this WG's arrival timestamp. The store-release's
        // wave-level waitcnt covers lanes 0..15's h stores (same wave).
        if (tid == 0) {
            __hip_atomic_store(flags + wg * 32, (unsigned int)(t + 1),
                               __ATOMIC_RELEASE, __HIP_MEMORY_SCOPE_AGENT);
        }
        // Wave 0 polls all 64 flags in parallel: lane L watches flag L.
        if (tid < 64) {
            const unsigned int target = (unsigned int)(t + 1);
            const unsigned int* myflag = flags + tid * 32;
            for (;;) {
                unsigned int v = __hip_atomic_load(myflag, __ATOMIC_RELAXED,
                                                   __HIP_MEMORY_SCOPE_AGENT);
                unsigned long long ready = __ballot(v >= target);
                if (ready == ~0ull) break;
            }
        }
        __syncthreads();
        __builtin_amdgcn_fence(__ATOMIC_ACQUIRE, "agent");
    }
}

// ---------------------------------------------------------------------------
extern "C" void kernel_launch(void* const* d_in, const int* in_sizes, int n_in,
                              void* d_out, int out_size, void* d_ws, size_t ws_size,
                              hipStream_t stream) {
    (void)in_sizes; (void)n_in; (void)out_size; (void)ws_size;
    const float* x    = (const float*)d_in[0];
    const float* wxf  = (const float*)d_in[1];
    const float* whf  = (const float*)d_in[2];
    const float* bf   = (const float*)d_in[3];
    const float* wxi  = (const float*)d_in[4];
    const float* whi  = (const float*)d_in[5];
    const float* bi   = (const float*)d_in[6];
    const float* wxc  = (const float*)d_in[7];
    const float* whc  = (const float*)d_in[8];
    const float* bc   = (const float*)d_in[9];
    const float* wxo  = (const float*)d_in[10];
    const float* who  = (const float*)d_in[11];
    const float* bo   = (const float*)d_in[12];
    const float* wy   = (const float*)d_in[13];
    const float* by   = (const float*)d_in[14];
    float* y_out = (float*)d_out;

    // Workspace layout (bytes)
    char* base = (char*)d_ws;
    float*  gx    = (float*)(base + 0);                       // 64 MB: [T][4H]
    float*  wxp   = (float*)(base + (size_t)64 * 1024 * 1024);// 8 MB
    float*  bpack = (float*)(base + (size_t)72 * 1024 * 1024);// 16 KB
    __half* wh16  = (__half*)(base + (size_t)72 * 1024 * 1024 + 16384); // 8 MB
    float*  hs    = (float*)(base + (size_t)80 * 1024 * 1024 + 16384);  // 16 MB
    __half* hbuf  = (__half*)(base + (size_t)96 * 1024 * 1024 + 16384); // 4 KB
    unsigned int* flags = (unsigned int*)(base + (size_t)96 * 1024 * 1024 + 16384 + 4096); // 8 KB

    // Zero h0 double-buffer + flag timestamps (ws is poisoned 0xAA each run).
    hipMemsetAsync(hbuf, 0, 4096 + 8192, stream);

    pack_wx_bias<<<(4 * H_DIM * I_DIM + 255) / 256, 256, 0, stream>>>(
        wxf, wxi, wxc, wxo, bf, bi, bc, bo, wxp, bpack);
    pack_wh_f16<<<(4 * H_DIM * H_DIM + 255) / 256, 256, 0, stream>>>(
        whf, whi, whc, who, wh16);

    // gx = x @ WxPack^T + bPack : [4096, 4096]
    gemm_bt<<<dim3((4 * H_DIM) / BN, T_DIM / BM), 256, 0, stream>>>(
        x, wxp, bpack, gx, T_DIM, 4 * H_DIM, I_DIM);

    lstm_recurrence<<<NWG, RTHREADS, 0, stream>>>(
        gx, (const unsigned int*)wh16, hbuf, hs, flags);

    // y = hs @ Wy^T + by : [4096, 256]
    gemm_bt<<<dim3(O_DIM / BN, T_DIM / BM), 256, 0, stream>>>(
        hs, wy, by, y_out, T_DIM, O_DIM, H_DIM);
}